// Round 9
// baseline (220.706 us; speedup 1.0000x reference)
//
#include <hip/hip_runtime.h>
#include <hip/hip_bf16.h>
#include <math.h>

// Fused GNN readout via bf16-split MFMA (v_mfma_f32_32x32x16_bf16):
//   feat1 = relu(concat(h,x) @ W1 + b1)   [N,256]  GEMM1: K=400(pad 448), A=bf16 hi, B=hi+lo
//   feat2 = relu(feat1 @ W2 + b2)         [N,64]   GEMM2: K=256, A=bf16 hi, B=hi+lo
//   s_n   = feat2 . Wout ; out = sigmoid(segment_sum(s_n) + bout)
// R9: deep counted-vmcnt pipeline — 5-buffer LDS ring, A issued 4 chunks
//     ahead; DISJOINT __shared__ arrays so alias analysis can never couple
//     buf-c ds_reads to loads into other bufs; 2 blocks/CU, 1024-reg budget.

typedef __attribute__((ext_vector_type(8)))  short short8v;
typedef __attribute__((ext_vector_type(16))) float f32x16;

#define G_NUM 2048
#define HID 200
#define EMB 200
#define DIN 400
#define NH1 256
#define NH2 64
#define BM  64
#define NKS1 28        // bf16 K-steps (of 16) for GEMM1, K padded 400->448
#define NCH  7         // 7 chunks of 64 fp32 cols
#define NKS2 16        // K-steps for GEMM2 (K=256)

#define W1P_SH8 (NKS1*8*64)   // 14336 fragments (16B each) per plane
#define W2P_SH8 (NKS2*2*64)   // 2048

__device__ __forceinline__ unsigned short f2bf(float f) {
    union { float f; unsigned u; } v; v.f = f;
    unsigned r = v.u + 0x7fffu + ((v.u >> 16) & 1u);   // RNE
    return (unsigned short)(r >> 16);
}
__device__ __forceinline__ float bf2f(unsigned short b) {
    union { unsigned u; float f; } v; v.u = ((unsigned)b) << 16;
    return v.f;
}
// 8 fp32 -> 8 bf16 (RNE) via packed converts
__device__ __forceinline__ short8v cvt8(float4 a, float4 b) {
    union { __hip_bfloat162 q[4]; short8v s8; } u;
    u.q[0] = __float22bfloat162_rn(make_float2(a.x, a.y));
    u.q[1] = __float22bfloat162_rn(make_float2(a.z, a.w));
    u.q[2] = __float22bfloat162_rn(make_float2(b.x, b.y));
    u.q[3] = __float22bfloat162_rn(make_float2(b.z, b.w));
    return u.s8;
}

// Pre-pack W1/W2 into MFMA-fragment order, hi/lo bf16 planes.
__global__ void pack_weights(const float* __restrict__ W1, const float* __restrict__ W2,
                             unsigned short* __restrict__ w1h, unsigned short* __restrict__ w1l,
                             unsigned short* __restrict__ w2h, unsigned short* __restrict__ w2l)
{
    int idx = blockIdx.x * 256 + threadIdx.x;
    if (idx < W1P_SH8) {
        int l  = idx & 63;
        int nt = (idx >> 6) & 7;
        int ks = idx >> 9;
        int col = nt * 32 + (l & 31);
        int k0  = ks * 16 + (l >> 5) * 8;
        short8v H, L;
        #pragma unroll
        for (int j = 0; j < 8; ++j) {
            int k = k0 + j;
            float v = (k < DIN) ? W1[(size_t)k * NH1 + col] : 0.f;
            unsigned short hh = f2bf(v);
            H[j] = (short)hh;
            L[j] = (short)f2bf(v - bf2f(hh));
        }
        ((short8v*)w1h)[idx] = H;
        ((short8v*)w1l)[idx] = L;
    } else if (idx < W1P_SH8 + W2P_SH8) {
        int i2 = idx - W1P_SH8;
        int l  = i2 & 63;
        int nt = (i2 >> 6) & 1;
        int ks = i2 >> 7;
        int col = nt * 32 + (l & 31);
        int k0  = ks * 16 + (l >> 5) * 8;
        short8v H, L;
        #pragma unroll
        for (int j = 0; j < 8; ++j) {
            float v = W2[(size_t)(k0 + j) * NH2 + col];
            unsigned short hh = f2bf(v);
            H[j] = (short)hh;
            L[j] = (short)f2bf(v - bf2f(hh));
        }
        ((short8v*)w2h)[i2] = H;
        ((short8v*)w2l)[i2] = L;
    }
}

__launch_bounds__(256, 2)
__global__ void fused_readout(const float* __restrict__ h, const float* __restrict__ x,
                              const int* __restrict__ batch,
                              const unsigned short* __restrict__ w1h, const unsigned short* __restrict__ w1l,
                              const unsigned short* __restrict__ w2h, const unsigned short* __restrict__ w2l,
                              const float* __restrict__ b1, const float* __restrict__ b2,
                              const float* __restrict__ Wout, const float* __restrict__ zbuf,
                              float* __restrict__ gf1d, int N)
{
    // 81920 B LDS: 5 DISJOINT ring buffers, each [64 rows][64 fp32] = 16 KiB.
    //   chunk c uses ring (c%5); A issued 4 chunks ahead.
    //   After the k-loop (full __syncthreads): F1h rows 0-31 -> R0,
    //   rows 32-63 -> R1 (bf16, XOR-swizzled); s2p/srow -> R2.
    __shared__ __align__(16) float R0[4096];
    __shared__ __align__(16) float R1[4096];
    __shared__ __align__(16) float R2[4096];
    __shared__ __align__(16) float R3[4096];
    __shared__ __align__(16) float R4[4096];

    const int t    = threadIdx.x;
    const int lane = t & 63;
    const int w    = t >> 6;
    const int n0   = blockIdx.x * BM;
    const int l31  = lane & 31;
    const int hs   = lane >> 5;         // k-half select

    const short8v* W1H = (const short8v*)w1h;
    const short8v* W1L = (const short8v*)w1l;

    f32x16 acc00, acc01, acc10, acc11;
    #pragma unroll
    for (int r = 0; r < 16; ++r) { acc00[r] = 0.f; acc01[r] = 0.f; acc10[r] = 0.f; acc11[r] = 0.f; }

    // ---- helpers ----
    // issue 4 global_load_lds covering this wave's 16 rows of chunk CH into ring RP
    // dest: linear  brow*256 + lane*16 bytes
    // src : per-lane, pre-swizzled col16 = (lane&15) ^ (row&15); OOB -> zbuf
    #define AISSUE(CH, RP) do {                                                \
        _Pragma("unroll")                                                      \
        for (int ii = 0; ii < 4; ++ii) {                                       \
            int brow = w*16 + ii*4;                                            \
            int row  = brow + (lane >> 4);                                     \
            int node = n0 + row;                                               \
            int colf = (CH)*64 + (((lane & 15) ^ (row & 15)) << 2);            \
            const float* src;                                                  \
            if (node >= N || colf >= DIN) src = zbuf + (lane & 15)*4;          \
            else if (colf < HID)          src = h + (size_t)node*HID + colf;   \
            else                          src = x + (size_t)node*EMB + (colf - HID); \
            __builtin_amdgcn_global_load_lds(                                  \
                (const __attribute__((address_space(1))) unsigned*)src,        \
                (__attribute__((address_space(3))) unsigned*)((char*)(RP) + brow*256 + lane*16), \
                16, 0, 0);                                                     \
        } } while (0)

    // A fragment: row ROW, logical col16 pair {S*4+hs*2, +1} of ring RP
    #define AFRAG(RP, S, ROW)                                                  \
        cvt8(*(const float4*)((const char*)(RP) + (ROW)*256 + ((((S)*4 + hs*2)     ^ ((ROW) & 15)) << 4)), \
             *(const float4*)((const char*)(RP) + (ROW)*256 + ((((S)*4 + hs*2 + 1) ^ ((ROW) & 15)) << 4)))

    #define BLOAD(KS, H0, H1, L0, L1) do {                                     \
        size_t nb_ = ((size_t)((KS)*8 + w*2))*64 + lane;                       \
        H0 = W1H[nb_]; H1 = W1H[nb_ + 64];                                     \
        L0 = W1L[nb_]; L1 = W1L[nb_ + 64]; } while (0)

    #define SSTEP(KSN, RP, S) do {                                             \
        short8v n2h0, n2h1, n2l0, n2l1;                                        \
        BLOAD((KSN), n2h0, n2h1, n2l0, n2l1);                                  \
        short8v ah0 = AFRAG(RP, S, l31);                                       \
        short8v ah1 = AFRAG(RP, S, 32 + l31);                                  \
        __builtin_amdgcn_s_setprio(1);                                         \
        acc00 = __builtin_amdgcn_mfma_f32_32x32x16_bf16(ah0, c0h0, acc00, 0,0,0); \
        acc00 = __builtin_amdgcn_mfma_f32_32x32x16_bf16(ah0, c0l0, acc00, 0,0,0); \
        acc01 = __builtin_amdgcn_mfma_f32_32x32x16_bf16(ah0, c0h1, acc01, 0,0,0); \
        acc01 = __builtin_amdgcn_mfma_f32_32x32x16_bf16(ah0, c0l1, acc01, 0,0,0); \
        acc10 = __builtin_amdgcn_mfma_f32_32x32x16_bf16(ah1, c0h0, acc10, 0,0,0); \
        acc10 = __builtin_amdgcn_mfma_f32_32x32x16_bf16(ah1, c0l0, acc10, 0,0,0); \
        acc11 = __builtin_amdgcn_mfma_f32_32x32x16_bf16(ah1, c0h1, acc11, 0,0,0); \
        acc11 = __builtin_amdgcn_mfma_f32_32x32x16_bf16(ah1, c0l1, acc11, 0,0,0); \
        __builtin_amdgcn_s_setprio(0);                                         \
        c0h0 = c1h0; c0h1 = c1h1; c0l0 = c1l0; c0l1 = c1l1;                    \
        c1h0 = n2h0; c1h1 = n2h1; c1l0 = n2l0; c1l1 = n2l1;                    \
    } while (0)

    // one chunk: wait A(C) (counted, never 0), barrier, optionally issue A(C+4)
    #define CHUNK(C, RCUR, VMC, DOISS, RISS) do {                              \
        asm volatile("s_waitcnt vmcnt(" #VMC ")" ::: "memory");                \
        __builtin_amdgcn_s_barrier();                                          \
        if (DOISS) AISSUE((C)+4, RISS);                                        \
        SSTEP((C)*4+2 < NKS1 ? (C)*4+2 : 0, RCUR, 0);                          \
        SSTEP((C)*4+3 < NKS1 ? (C)*4+3 : 0, RCUR, 1);                          \
        SSTEP((C)*4+4 < NKS1 ? (C)*4+4 : 0, RCUR, 2);                          \
        SSTEP((C)*4+5 < NKS1 ? (C)*4+5 : 0, RCUR, 3);                          \
    } while (0)

    // ---- prologue: A chunks 0..3 in flight; B ksteps 0,1 in flight ----
    AISSUE(0, R0);
    AISSUE(1, R1);
    AISSUE(2, R2);
    AISSUE(3, R3);
    short8v c0h0, c0h1, c0l0, c0l1;    // B(ks)   — consumed this k-step
    short8v c1h0, c1h1, c1l0, c1l1;    // B(ks+1)
    BLOAD(0, c0h0, c0h1, c0l0, c0l1);
    BLOAD(1, c1h0, c1h1, c1l0, c1l1);

    // ================= GEMM1: 7 chunks x 4 k-steps, 4-deep pipeline =================
    // vmcnt at chunk C must leave outstanding: A issued after A(C) + 8 B loads.
    CHUNK(0, R0, 20, true,  R4);   // newer: A1,A2,A3 (12) + B (8)
    CHUNK(1, R1, 20, true,  R0);   // newer: A2,A3,A4 (12) + B (8)
    CHUNK(2, R2, 20, true,  R1);   // newer: A3,A4,A5 (12) + B (8)
    CHUNK(3, R3, 20, false, R0);   // newer: A4,A5,A6 (12) + B (8)
    CHUNK(4, R4, 16, false, R0);   // newer: A5,A6 (8) + B (8)
    CHUNK(5, R0, 12, false, R0);   // newer: A6 (4) + B (8)
    CHUNK(6, R1,  8, false, R0);   // newer: B (8)

    #undef CHUNK
    #undef SSTEP
    #undef BLOAD
    #undef AFRAG
    #undef AISSUE

    __syncthreads();   // all ring reads done; full drain ok (one-time)

    // ---- epilogue1: bias + relu + bf16 (hi only) -> F1h (XOR-swizzled) ----
    // F1h rows 0-31 -> R0, rows 32-63 -> R1.
    // C/D layout: col = lane&31, row = (r&3) + 8*(r>>2) + 4*(lane>>5)
    unsigned short* F1hA = (unsigned short*)R0;
    unsigned short* F1hB = (unsigned short*)R1;
    const float b1c0 = b1[w*64 + l31];
    const float b1c1 = b1[w*64 + 32 + l31];
#define EPI1(ACC, FH, NI) do {                                            \
        int gcol = w*64 + (NI)*32 + l31;                                  \
        float bb = (NI) ? b1c1 : b1c0;                                    \
        _Pragma("unroll")                                                 \
        for (int r = 0; r < 16; ++r) {                                    \
            int lrow = (r & 3) + 8*(r >> 2) + 4*hs;   /* 0..31 */         \
            float v = fmaxf(ACC[r] + bb, 0.f);                            \
            int phys = lrow*256 + (((gcol >> 3) ^ lrow) << 3) + (gcol & 7); \
            FH[phys] = f2bf(v);                                           \
        } } while (0)
    EPI1(acc00, F1hA, 0); EPI1(acc01, F1hA, 1); EPI1(acc10, F1hB, 0); EPI1(acc11, F1hB, 1);
#undef EPI1
    __syncthreads();

    // ================= GEMM2: feat2 = relu(feat1 @ W2 + b2) =================
    // A = bf16(feat1) hi-only; B = W2 hi+lo (2 MFMAs per K-step).
    f32x16 acc2;
    #pragma unroll
    for (int r = 0; r < 16; ++r) acc2[r] = 0.f;
    const int m2   = w >> 1;      // node-row half
    const int nt2  = w & 1;       // col half
    const unsigned short* F1rd = m2 ? F1hB : F1hA;   // local rows 0..31 = l31

    const short8v* W2H = (const short8v*)w2h;
    const short8v* W2L = (const short8v*)w2l;
    short8v bhc = W2H[(size_t)nt2*64 + lane];
    short8v blc = W2L[(size_t)nt2*64 + lane];
    #pragma unroll
    for (int ks = 0; ks < NKS2; ++ks) {
        short8v bhn = bhc, bln = blc;
        if (ks + 1 < NKS2) {
            size_t nbase = (size_t)((ks + 1)*2 + nt2)*64 + lane;
            bhn = W2H[nbase];
            bln = W2L[nbase];
        }
        int blk  = (ks*2 + hs) ^ l31;
        short8v ah2 = *(const short8v*)&F1rd[l31*256 + blk*8];
        acc2 = __builtin_amdgcn_mfma_f32_32x32x16_bf16(ah2, bhc, acc2, 0,0,0);
        acc2 = __builtin_amdgcn_mfma_f32_32x32x16_bf16(ah2, blc, acc2, 0,0,0);
        bhc = bhn; blc = bln;
    }
    __syncthreads();   // all F1 reads done

    // ---- epilogue2: s_n = relu(feat2 + b2) . Wout, 32-col shfl reduce ----
    float* s2p  = R2;          // 128 floats
    float* srow = R2 + 128;    // 64 floats
    {
        const int   col2 = nt2*32 + l31;
        const float b2c  = b2[col2];
        const float woc  = Wout[col2];
        #pragma unroll
        for (int r = 0; r < 16; ++r) {
            float v = fmaxf(acc2[r] + b2c, 0.f) * woc;
            v += __shfl_xor(v, 1);
            v += __shfl_xor(v, 2);
            v += __shfl_xor(v, 4);
            v += __shfl_xor(v, 8);
            v += __shfl_xor(v, 16);
            if (l31 == 0) {
                int grow = m2*32 + (r & 3) + 8*(r >> 2) + 4*hs;
                s2p[nt2*64 + grow] = v;   // [colhalf][row]
            }
        }
    }
    __syncthreads();
    if (t < 64) srow[t] = s2p[t] + s2p[64 + t];
    __syncthreads();

    // ---- segmented sum over sorted batch, one atomic per run ----
    if (t < 64) {
        int node = n0 + t;
        int b = (node < N) ? batch[node] : -1;
        int pb = (t == 0) ? -2 : ((node - 1 < N) ? batch[node - 1] : -1);
        if (b >= 0 && b != pb) {
            float acc = 0.f;
            int j = t;
            while (j < 64 && (n0 + j) < N && batch[n0 + j] == b) { acc += srow[j]; ++j; }
            atomicAdd(&gf1d[b], acc);
        }
    }
}

__global__ void final_sigmoid(const float* __restrict__ gf1d, const float* __restrict__ bout,
                              float* __restrict__ out, int G)
{
    int g = blockIdx.x * 256 + threadIdx.x;
    if (g < G) out[g] = 1.f / (1.f + expf(-(gf1d[g] + bout[0])));
}

extern "C" void kernel_launch(void* const* d_in, const int* in_sizes, int n_in,
                              void* d_out, int out_size, void* d_ws, size_t ws_size,
                              hipStream_t stream)
{
    const float* h    = (const float*)d_in[0];
    const float* x    = (const float*)d_in[1];
    const int*   batch= (const int*)d_in[2];
    const float* W1   = (const float*)d_in[3];
    const float* b1   = (const float*)d_in[4];
    const float* W2   = (const float*)d_in[5];
    const float* b2   = (const float*)d_in[6];
    const float* Wout = (const float*)d_in[7];
    const float* bout = (const float*)d_in[8];
    float* out = (float*)d_out;

    const int N = in_sizes[2];
    const int G = out_size;

    // workspace layout (~533 KB total)
    char* ws = (char*)d_ws;
    float* gf1d = (float*)ws;                                  //   8,192 B
    float* zbuf = (float*)(ws + 8192);                         //   1,024 B (zeros)
    unsigned short* w1h = (unsigned short*)(ws + 9216);        // 229,376 B
    unsigned short* w1l = w1h + (size_t)W1P_SH8 * 8;           // 229,376 B
    unsigned short* w2h = w1l + (size_t)W1P_SH8 * 8;           //  32,768 B
    unsigned short* w2l = w2h + (size_t)W2P_SH8 * 8;           //  32,768 B

    hipMemsetAsync(gf1d, 0, 9216, stream);   // gf accumulators + zero buffer
    pack_weights<<<(W1P_SH8 + W2P_SH8 + 255) / 256, 256, 0, stream>>>(W1, W2, w1h, w1l, w2h, w2l);
    fused_readout<<<(N + BM - 1) / BM, 256, 0, stream>>>(h, x, batch, w1h, w1l, w2h, w2l,
                                                         b1, b2, Wout, zbuf, gf1d, N);
    final_sigmoid<<<(G + 255) / 256, 256, 0, stream>>>(gf1d, bout, out, G);
}